// Round 5
// baseline (132.895 us; speedup 1.0000x reference)
//
#include <hip/hip_runtime.h>

#define TSTEPS 1024
#define NROWS  8192
#define CLEN   16      // steps per lane-chunk
#define KEPS   1e-6f

__device__ __forceinline__ float clampP(float x) {
    return fminf(fmaxf(x, KEPS), 1.f - KEPS);
}
__device__ __forceinline__ float sigm(float v) {
    return 1.0f / (1.0f + __expf(-v));
}

// One wave = one row, fully independent (no barriers):
//  A) MLP: lane = hidden unit; embed row in per-wave LDS slice; W-columns coalesced (L2-hot).
//     xor-butterfly head reduction -> l,g,s,prior wave-uniform in all lanes.
//  B) lane = 16-step time chunk: build y-bitmask from one int4x4 (64B) load.
//  C) compose 16 step Mobius matrices (renorm every 4; m11>0 provably).
//  D) 6-step Hillis-Steele wave prefix over chunk matrices -> chunk-start latents.
//  E) exact clipped recurrence for 16 steps; two float4 stores per 16-B window,
//     each lane covers exactly one 64-B line -> clean write merging.
__global__ __launch_bounds__(256) void bkt_onewave(
    const int* __restrict__ X, const int* __restrict__ y,
    const float* __restrict__ embed,
    const float* __restrict__ W0, const float* __restrict__ b0,
    const float* __restrict__ W1, const float* __restrict__ b1,
    const float* __restrict__ Wout, const float* __restrict__ bout,
    float* __restrict__ out_corr, float* __restrict__ out_lat)
{
    const int lane = threadIdx.x & 63;
    const int wid  = threadIdx.x >> 6;
    const int row  = blockIdx.x * 4 + wid;

    __shared__ float sh[4][64];   // per-wave 256B slice; within-wave RAW only

    // ---- B(load): my chunk's 16 y values, issued early ----
    const int4* yb = (const int4*)(y + (size_t)row * TSTEPS + lane * CLEN);
    const int4 v0 = yb[0], v1 = yb[1], v2 = yb[2], v3 = yb[3];
    unsigned msk = 0;
    msk |= (v0.x > 0) ? 1u << 0  : 0u; msk |= (v0.y > 0) ? 1u << 1  : 0u;
    msk |= (v0.z > 0) ? 1u << 2  : 0u; msk |= (v0.w > 0) ? 1u << 3  : 0u;
    msk |= (v1.x > 0) ? 1u << 4  : 0u; msk |= (v1.y > 0) ? 1u << 5  : 0u;
    msk |= (v1.z > 0) ? 1u << 6  : 0u; msk |= (v1.w > 0) ? 1u << 7  : 0u;
    msk |= (v2.x > 0) ? 1u << 8  : 0u; msk |= (v2.y > 0) ? 1u << 9  : 0u;
    msk |= (v2.z > 0) ? 1u << 10 : 0u; msk |= (v2.w > 0) ? 1u << 11 : 0u;
    msk |= (v3.x > 0) ? 1u << 12 : 0u; msk |= (v3.y > 0) ? 1u << 13 : 0u;
    msk |= (v3.z > 0) ? 1u << 14 : 0u; msk |= (v3.w > 0) ? 1u << 15 : 0u;

    // ---- A: MLP for my row ----
    const int skill = X[row];                        // wave-uniform
    sh[wid][lane] = embed[(size_t)skill * 64 + lane];

    float acc = b0[lane];
    #pragma unroll
    for (int k4 = 0; k4 < 16; ++k4) {
        const float4 e = *(const float4*)&sh[wid][k4 * 4];   // LDS broadcast
        acc = fmaf(e.x, W0[(k4 * 4 + 0) * 64 + lane], acc);
        acc = fmaf(e.y, W0[(k4 * 4 + 1) * 64 + lane], acc);
        acc = fmaf(e.z, W0[(k4 * 4 + 2) * 64 + lane], acc);
        acc = fmaf(e.w, W0[(k4 * 4 + 3) * 64 + lane], acc);
    }
    sh[wid][lane] = fmaxf(acc, 0.f);                 // within-wave ordering via lgkmcnt

    acc = b1[lane];
    #pragma unroll
    for (int k4 = 0; k4 < 16; ++k4) {
        const float4 e = *(const float4*)&sh[wid][k4 * 4];
        acc = fmaf(e.x, W1[(k4 * 4 + 0) * 64 + lane], acc);
        acc = fmaf(e.y, W1[(k4 * 4 + 1) * 64 + lane], acc);
        acc = fmaf(e.z, W1[(k4 * 4 + 2) * 64 + lane], acc);
        acc = fmaf(e.w, W1[(k4 * 4 + 3) * 64 + lane], acc);
    }
    const float h1v = fmaxf(acc, 0.f);

    const float4 wo = ((const float4*)Wout)[lane];
    float p0 = h1v * wo.x, p1 = h1v * wo.y, p2 = h1v * wo.z, p3 = h1v * wo.w;
    #pragma unroll
    for (int off = 32; off >= 1; off >>= 1) {
        p0 += __shfl_xor(p0, off, 64);
        p1 += __shfl_xor(p1, off, 64);
        p2 += __shfl_xor(p2, off, 64);
        p3 += __shfl_xor(p3, off, 64);
    }
    const float4 bo = *(const float4*)bout;
    const float l     = clampP(sigm(p0 + bo.x));
    const float g     = clampP(sigm(p1 + bo.y));
    const float s     = clampP(sigm(p2 + bo.z));
    const float prior = clampP(sigm(p3 + bo.w));

    // step as Mobius: L' = (m00*L+m01)/(m10*L+m11)
    const float c1 = 1.f - s - g, d1 = g;             // y=1
    const float e00_1 = fmaf(l, c1, (1.f - l) * (1.f - s));
    const float e01_1 = l * d1;
    const float c0 = s + g - 1.f, d0 = 1.f - g;       // y=0
    const float e00_0 = fmaf(l, c0, (1.f - l) * s);
    const float e01_0 = l * d0;

    // ---- C: compose my chunk's 16 step matrices ----
    float m00 = 1.f, m01 = 0.f, m10 = 0.f, m11 = 1.f;
    #pragma unroll
    for (int t = 0; t < CLEN; ++t) {
        const bool one = (msk >> t) & 1u;
        const float e00 = one ? e00_1 : e00_0;
        const float e01 = one ? e01_1 : e01_0;
        const float e10 = one ? c1 : c0;
        const float e11 = one ? d1 : d0;
        const float n00 = fmaf(e00, m00, e01 * m10);
        const float n01 = fmaf(e00, m01, e01 * m11);
        const float n10 = fmaf(e10, m00, e11 * m10);
        const float n11 = fmaf(e10, m01, e11 * m11);
        if ((t & 3) == 3) {
            const float inv = __builtin_amdgcn_rcpf(n11);
            m00 = n00 * inv; m01 = n01 * inv; m10 = n10 * inv; m11 = 1.f;
        } else {
            m00 = n00; m01 = n01; m10 = n10; m11 = n11;
        }
    }

    // ---- D: inclusive Hillis-Steele prefix over 64 chunk matrices ----
    float s00 = m00, s01 = m01, s10 = m10, s11 = m11;
    #pragma unroll
    for (int d = 1; d < 64; d <<= 1) {
        const float t00 = __shfl_up(s00, d, 64);
        const float t01 = __shfl_up(s01, d, 64);
        const float t10 = __shfl_up(s10, d, 64);
        const float t11 = __shfl_up(s11, d, 64);
        if (lane >= d) {
            const float r00 = fmaf(s00, t00, s01 * t10);
            const float r01 = fmaf(s00, t01, s01 * t11);
            const float r10 = fmaf(s10, t00, s11 * t10);
            const float r11 = fmaf(s10, t01, s11 * t11);
            const float inv = __builtin_amdgcn_rcpf(r11);
            s00 = r00 * inv; s01 = r01 * inv; s10 = r10 * inv; s11 = 1.f;
        }
    }
    const float x00 = __shfl_up(s00, 1, 64);
    const float x01 = __shfl_up(s01, 1, 64);
    const float x10 = __shfl_up(s10, 1, 64);
    const float x11 = __shfl_up(s11, 1, 64);
    float L0;
    if (lane == 0) {
        L0 = prior;
    } else {
        const float num = fmaf(x00, prior, x01);
        const float den = fmaf(x10, prior, x11);
        L0 = clampP(num * __builtin_amdgcn_rcpf(den));
    }

    // ---- E: exact clipped recurrence; one 64B line per lane per output array ----
    const float a   = 1.f - s;
    const float omg = 1.f - g;
    const float oml = 1.f - l;
    float* oc = out_corr + (size_t)row * TSTEPS + lane * CLEN;
    float* ol = out_lat  + (size_t)row * TSTEPS + lane * CLEN;
    float Lc = L0;
    #pragma unroll
    for (int w = 0; w < 4; ++w) {
        float cr[4], lt[4];
        #pragma unroll
        for (int q = 0; q < 4; ++q) {
            const int t = w * 4 + q;
            const float correct = fmaf(Lc, c1, g);
            const float den0    = fmaf(Lc, c0, omg);
            const float k1 = (Lc * a) * __builtin_amdgcn_rcpf(correct);
            const float k0 = (Lc * s) * __builtin_amdgcn_rcpf(den0);
            const bool one = (msk >> t) & 1u;
            const float k = one ? k1 : k0;
            cr[q] = correct;
            lt[q] = Lc;
            Lc = clampP(fmaf(k, oml, l));
        }
        *(float4*)(oc + w * 4) = make_float4(cr[0], cr[1], cr[2], cr[3]);
        *(float4*)(ol + w * 4) = make_float4(lt[0], lt[1], lt[2], lt[3]);
    }
}

extern "C" void kernel_launch(void* const* d_in, const int* in_sizes, int n_in,
                              void* d_out, int out_size, void* d_ws, size_t ws_size,
                              hipStream_t stream) {
    const int*   X     = (const int*)  d_in[0];
    const int*   y     = (const int*)  d_in[1];
    const float* embed = (const float*)d_in[2];
    const float* W0    = (const float*)d_in[3];
    const float* b0    = (const float*)d_in[4];
    const float* W1    = (const float*)d_in[5];
    const float* b1    = (const float*)d_in[6];
    const float* Wout  = (const float*)d_in[7];
    const float* bout  = (const float*)d_in[8];

    float* out_corr = (float*)d_out;
    float* out_lat  = out_corr + (size_t)NROWS * TSTEPS;

    bkt_onewave<<<NROWS / 4, 256, 0, stream>>>(X, y, embed, W0, b0, W1, b1, Wout, bout,
                                               out_corr, out_lat);
}

// Round 6
// 132.807 us; speedup vs baseline: 1.0007x; 1.0007x over previous
//
#include <hip/hip_runtime.h>

#define TSTEPS 1024
#define NROWS  8192
#define CLEN   16      // steps per lane-chunk
#define KEPS   1e-6f

__device__ __forceinline__ float clampP(float x) {
    return fminf(fmaxf(x, KEPS), 1.f - KEPS);
}
__device__ __forceinline__ float sigm(float v) {
    return 1.0f / (1.0f + __expf(-v));
}

// ---------------- K1: per-row MLP -> params {l,g,s,prior}; 4 rows/wave (v4, known-good) ----
__global__ __launch_bounds__(256) void bkt_params_v6(
    const int* __restrict__ X, const float* __restrict__ embed,
    const float* __restrict__ W0, const float* __restrict__ b0,
    const float* __restrict__ W1, const float* __restrict__ b1,
    const float* __restrict__ Wout, const float* __restrict__ bout,
    float4* __restrict__ params)
{
    const int lane    = threadIdx.x & 63;
    const int wid     = threadIdx.x >> 6;
    const int rowbase = blockIdx.x * 16 + wid * 4;

    __shared__ float sh[4][4][64];
    float (*shw)[64] = sh[wid];

    #pragma unroll
    for (int rs = 0; rs < 4; ++rs) {
        const int skill = X[rowbase + rs];
        shw[rs][lane] = embed[(size_t)skill * 64 + lane];
    }
    __syncthreads();

    float a0 = b0[lane], a1 = a0, a2 = a0, a3 = a0;
    #pragma unroll
    for (int k4 = 0; k4 < 16; ++k4) {
        const float4 e0 = *(const float4*)&shw[0][k4 * 4];
        const float4 e1 = *(const float4*)&shw[1][k4 * 4];
        const float4 e2 = *(const float4*)&shw[2][k4 * 4];
        const float4 e3 = *(const float4*)&shw[3][k4 * 4];
        const float w0 = W0[(k4 * 4 + 0) * 64 + lane];
        const float w1 = W0[(k4 * 4 + 1) * 64 + lane];
        const float w2 = W0[(k4 * 4 + 2) * 64 + lane];
        const float w3 = W0[(k4 * 4 + 3) * 64 + lane];
        a0 = fmaf(e0.x, w0, a0); a0 = fmaf(e0.y, w1, a0); a0 = fmaf(e0.z, w2, a0); a0 = fmaf(e0.w, w3, a0);
        a1 = fmaf(e1.x, w0, a1); a1 = fmaf(e1.y, w1, a1); a1 = fmaf(e1.z, w2, a1); a1 = fmaf(e1.w, w3, a1);
        a2 = fmaf(e2.x, w0, a2); a2 = fmaf(e2.y, w1, a2); a2 = fmaf(e2.z, w2, a2); a2 = fmaf(e2.w, w3, a2);
        a3 = fmaf(e3.x, w0, a3); a3 = fmaf(e3.y, w1, a3); a3 = fmaf(e3.z, w2, a3); a3 = fmaf(e3.w, w3, a3);
    }
    __syncthreads();
    shw[0][lane] = fmaxf(a0, 0.f);
    shw[1][lane] = fmaxf(a1, 0.f);
    shw[2][lane] = fmaxf(a2, 0.f);
    shw[3][lane] = fmaxf(a3, 0.f);
    __syncthreads();

    a0 = b1[lane]; a1 = a0; a2 = a0; a3 = a0;
    #pragma unroll
    for (int k4 = 0; k4 < 16; ++k4) {
        const float4 e0 = *(const float4*)&shw[0][k4 * 4];
        const float4 e1 = *(const float4*)&shw[1][k4 * 4];
        const float4 e2 = *(const float4*)&shw[2][k4 * 4];
        const float4 e3 = *(const float4*)&shw[3][k4 * 4];
        const float w0 = W1[(k4 * 4 + 0) * 64 + lane];
        const float w1 = W1[(k4 * 4 + 1) * 64 + lane];
        const float w2 = W1[(k4 * 4 + 2) * 64 + lane];
        const float w3 = W1[(k4 * 4 + 3) * 64 + lane];
        a0 = fmaf(e0.x, w0, a0); a0 = fmaf(e0.y, w1, a0); a0 = fmaf(e0.z, w2, a0); a0 = fmaf(e0.w, w3, a0);
        a1 = fmaf(e1.x, w0, a1); a1 = fmaf(e1.y, w1, a1); a1 = fmaf(e1.z, w2, a1); a1 = fmaf(e1.w, w3, a1);
        a2 = fmaf(e2.x, w0, a2); a2 = fmaf(e2.y, w1, a2); a2 = fmaf(e2.z, w2, a2); a2 = fmaf(e2.w, w3, a2);
        a3 = fmaf(e3.x, w0, a3); a3 = fmaf(e3.y, w1, a3); a3 = fmaf(e3.z, w2, a3); a3 = fmaf(e3.w, w3, a3);
    }
    const float h0r = fmaxf(a0, 0.f), h1r = fmaxf(a1, 0.f);
    const float h2r = fmaxf(a2, 0.f), h3r = fmaxf(a3, 0.f);

    const float4 wo = ((const float4*)Wout)[lane];
    float p[4][4];
    p[0][0] = h0r * wo.x; p[0][1] = h0r * wo.y; p[0][2] = h0r * wo.z; p[0][3] = h0r * wo.w;
    p[1][0] = h1r * wo.x; p[1][1] = h1r * wo.y; p[1][2] = h1r * wo.z; p[1][3] = h1r * wo.w;
    p[2][0] = h2r * wo.x; p[2][1] = h2r * wo.y; p[2][2] = h2r * wo.z; p[2][3] = h2r * wo.w;
    p[3][0] = h3r * wo.x; p[3][1] = h3r * wo.y; p[3][2] = h3r * wo.z; p[3][3] = h3r * wo.w;
    #pragma unroll
    for (int off = 32; off >= 1; off >>= 1) {
        #pragma unroll
        for (int rs = 0; rs < 4; ++rs)
            #pragma unroll
            for (int c = 0; c < 4; ++c)
                p[rs][c] += __shfl_xor(p[rs][c], off, 64);
    }
    const float4 bo = *(const float4*)bout;
    float v0 = (lane == 0) ? p[0][0] : (lane == 1) ? p[1][0] : (lane == 2) ? p[2][0] : p[3][0];
    float v1 = (lane == 0) ? p[0][1] : (lane == 1) ? p[1][1] : (lane == 2) ? p[2][1] : p[3][1];
    float v2 = (lane == 0) ? p[0][2] : (lane == 1) ? p[1][2] : (lane == 2) ? p[2][2] : p[3][2];
    float v3 = (lane == 0) ? p[0][3] : (lane == 1) ? p[1][3] : (lane == 2) ? p[2][3] : p[3][3];
    if (lane < 4) {
        float4 r;
        r.x = clampP(sigm(v0 + bo.x));
        r.y = clampP(sigm(v1 + bo.y));
        r.z = clampP(sigm(v2 + bo.z));
        r.w = clampP(sigm(v3 + bo.w));
        params[rowbase + lane] = r;
    }
}

// ---------------- K2: scan, ROLLED loops (small I-footprint), single-rcp step ----
__global__ __launch_bounds__(256) void bkt_scan_v6(
    const int* __restrict__ y, const float4* __restrict__ params,
    float* __restrict__ out_corr, float* __restrict__ out_lat)
{
    const int lane = threadIdx.x & 63;
    const int row  = blockIdx.x * 4 + (threadIdx.x >> 6);

    const float4 p = params[row];

    // my chunk's 16 y values (64 B contiguous per lane)
    const int4* yb = (const int4*)(y + (size_t)row * TSTEPS + lane * CLEN);
    const int4 v0 = yb[0], v1 = yb[1], v2 = yb[2], v3 = yb[3];
    unsigned msk = 0;
    msk |= (v0.x > 0) ? 1u << 0  : 0u; msk |= (v0.y > 0) ? 1u << 1  : 0u;
    msk |= (v0.z > 0) ? 1u << 2  : 0u; msk |= (v0.w > 0) ? 1u << 3  : 0u;
    msk |= (v1.x > 0) ? 1u << 4  : 0u; msk |= (v1.y > 0) ? 1u << 5  : 0u;
    msk |= (v1.z > 0) ? 1u << 6  : 0u; msk |= (v1.w > 0) ? 1u << 7  : 0u;
    msk |= (v2.x > 0) ? 1u << 8  : 0u; msk |= (v2.y > 0) ? 1u << 9  : 0u;
    msk |= (v2.z > 0) ? 1u << 10 : 0u; msk |= (v2.w > 0) ? 1u << 11 : 0u;
    msk |= (v3.x > 0) ? 1u << 12 : 0u; msk |= (v3.y > 0) ? 1u << 13 : 0u;
    msk |= (v3.z > 0) ? 1u << 14 : 0u; msk |= (v3.w > 0) ? 1u << 15 : 0u;

    const float l = p.x, g = p.y, s = p.z, prior = p.w;

    // step as Mobius: L' = (m00*L+m01)/(m10*L+m11)
    const float c1 = 1.f - s - g, d1 = g;             // y=1
    const float e00_1 = fmaf(l, c1, (1.f - l) * (1.f - s));
    const float e01_1 = l * d1;
    const float c0 = s + g - 1.f, d0 = 1.f - g;       // y=0
    const float e00_0 = fmaf(l, c0, (1.f - l) * s);
    const float e01_0 = l * d0;

    // ---- Phase C: compose my 16 step matrices; rolled 4x(4-step + renorm) ----
    float m00 = 1.f, m01 = 0.f, m10 = 0.f, m11 = 1.f;
    unsigned mmc = msk;
    for (int t4 = 0; t4 < 4; ++t4) {
        #pragma unroll
        for (int q = 0; q < 4; ++q) {
            const bool one = mmc & 1u; mmc >>= 1;
            const float e00 = one ? e00_1 : e00_0;
            const float e01 = one ? e01_1 : e01_0;
            const float e10 = one ? c1 : c0;
            const float e11 = one ? d1 : d0;
            const float n00 = fmaf(e00, m00, e01 * m10);
            const float n01 = fmaf(e00, m01, e01 * m11);
            const float n10 = fmaf(e10, m00, e11 * m10);
            const float n11 = fmaf(e10, m01, e11 * m11);
            m00 = n00; m01 = n01; m10 = n10; m11 = n11;
        }
        const float inv = __builtin_amdgcn_rcpf(m11);   // m11 > 0 (positive denominators)
        m00 *= inv; m01 *= inv; m10 *= inv; m11 = 1.f;
    }

    // ---- Phase D: inclusive Hillis-Steele prefix over 64 chunk matrices; rolled ----
    float s00 = m00, s01 = m01, s10 = m10, s11 = m11;
    for (int d = 1; d < 64; d <<= 1) {
        const float t00 = __shfl_up(s00, d, 64);
        const float t01 = __shfl_up(s01, d, 64);
        const float t10 = __shfl_up(s10, d, 64);
        const float t11 = __shfl_up(s11, d, 64);
        if (lane >= d) {
            const float r00 = fmaf(s00, t00, s01 * t10);
            const float r01 = fmaf(s00, t01, s01 * t11);
            const float r10 = fmaf(s10, t00, s11 * t10);
            const float r11 = fmaf(s10, t01, s11 * t11);
            const float inv = __builtin_amdgcn_rcpf(r11);
            s00 = r00 * inv; s01 = r01 * inv; s10 = r10 * inv; s11 = 1.f;
        }
    }
    const float x00 = __shfl_up(s00, 1, 64);
    const float x01 = __shfl_up(s01, 1, 64);
    const float x10 = __shfl_up(s10, 1, 64);
    const float x11 = __shfl_up(s11, 1, 64);
    float L0;
    if (lane == 0) {
        L0 = prior;
    } else {
        const float num = fmaf(x00, prior, x01);
        const float den = fmaf(x10, prior, x11);
        L0 = clampP(num * __builtin_amdgcn_rcpf(den));
    }

    // ---- Phase E: exact clipped recurrence, single rcp per step; rolled 4x4 ----
    const float a   = 1.f - s;
    const float omg = 1.f - g;
    const float oml = 1.f - l;
    float* oc = out_corr + (size_t)row * TSTEPS + lane * CLEN;
    float* ol = out_lat  + (size_t)row * TSTEPS + lane * CLEN;
    float Lc = L0;
    unsigned mme = msk;
    for (int w = 0; w < 4; ++w) {
        float cr[4], lt[4];
        #pragma unroll
        for (int q = 0; q < 4; ++q) {
            const float correct = fmaf(Lc, c1, g);    // L*(1-s-g)+g
            const float den0    = fmaf(Lc, c0, omg);  // L*(s+g-1)+(1-g)
            const bool one = mme & 1u; mme >>= 1;
            const float numf = Lc * (one ? a : s);
            const float den  = one ? correct : den0;
            const float k = numf * __builtin_amdgcn_rcpf(den);
            cr[q] = correct;
            lt[q] = Lc;
            Lc = clampP(fmaf(k, oml, l));
        }
        *(float4*)(oc + w * 4) = make_float4(cr[0], cr[1], cr[2], cr[3]);
        *(float4*)(ol + w * 4) = make_float4(lt[0], lt[1], lt[2], lt[3]);
    }
}

extern "C" void kernel_launch(void* const* d_in, const int* in_sizes, int n_in,
                              void* d_out, int out_size, void* d_ws, size_t ws_size,
                              hipStream_t stream) {
    const int*   X     = (const int*)  d_in[0];
    const int*   y     = (const int*)  d_in[1];
    const float* embed = (const float*)d_in[2];
    const float* W0    = (const float*)d_in[3];
    const float* b0    = (const float*)d_in[4];
    const float* W1    = (const float*)d_in[5];
    const float* b1    = (const float*)d_in[6];
    const float* Wout  = (const float*)d_in[7];
    const float* bout  = (const float*)d_in[8];

    float* out_corr = (float*)d_out;
    float* out_lat  = out_corr + (size_t)NROWS * TSTEPS;
    float4* paramsb = (float4*)d_ws;   // 128 KB scratch

    bkt_params_v6<<<NROWS / 16, 256, 0, stream>>>(X, embed, W0, b0, W1, b1, Wout, bout, paramsb);
    bkt_scan_v6 <<<NROWS / 4,  256, 0, stream>>>(y, paramsb, out_corr, out_lat);
}